// Round 3
// baseline (358.267 us; speedup 1.0000x reference)
//
#include <hip/hip_runtime.h>

#define BB   128
#define JJ   17
#define YY   96
#define XX   72
#define YX   (YY * XX)        // 6912 floats per (b,j) per channel
#define N4   (YX / 4)         // 1728 float4s
#define NQ   (BB * JJ)        // 2176 blocks / partials
#define NTOT (NQ * YX)        // 15040512 elements per channel
#define UNI  6                // uniform float4 iters/thread (6*256 = 1536)
#define TAIL (N4 - UNI * 256) // 192 remaining float4s (threads 0..191)
#define CTR_OFF 16384         // counter offset in d_ws (past the partials)

typedef float f32x4 __attribute__((ext_vector_type(4)));

// Sum of squared diffs for one float4 pair at float4-index i within a q-tile.
// yy = (4i)/72 = i/18 ; xx = (i%18)*4.
// gt uses trunc-toward-zero (np int32 cast) == truncf for |z| < 2^31; we use
// v_trunc_f32 (1 instr) instead of cvt_i32_f32(cvt_f32_i32(z)) (2 instrs).
// Operand order fl((x+k) - cx) kept bit-identical to the reference.
__device__ __forceinline__ float tile_term(f32x4 lx, f32x4 ly, int i,
                                           float cx, float cy) {
    const int yy = i / 18;                // magic-mul constant divide
    const int xx = (i - yy * 18) * 4;
    const float gy = truncf((float)yy - cy);
    const float xxf = (float)xx;
    float s = 0.0f;
    #pragma unroll
    for (int k = 0; k < 4; ++k) {
        const float gx = truncf((xxf + (float)k) - cx);  // (float)(xx+k) exact
        const float dx = lx[k] - gx;
        s = fmaf(dx, dx, s);
        const float dy = ly[k] - gy;
        s = fmaf(dy, dy, s);
    }
    return s;
}

// One block per q = b*J + j (round-0 geometry, plain float4 loads — the
// nontemporal experiment regressed 6x: nt on ext-vectors breaks the dwordx4
// path / bypasses caches with poor MLP. Normal loads measured ~4.3 TB/s.)
// Final reduction fused via last-block-done ticket (deterministic sum order,
// verified absmax=0 in round 2).
__global__ __launch_bounds__(256) void regloss_fused_kernel(
    const float* __restrict__ loc,    // (2, B, J, Y, X)
    const float* __restrict__ cord,   // (2, J, B)
    const float* __restrict__ tw,     // (B, J, 1)
    float* __restrict__ partial,      // (NQ,) in d_ws
    unsigned* __restrict__ counter,   // 1 u32 in d_ws, memset to 0 pre-launch
    float* __restrict__ out)
{
    const int tid = threadIdx.x;
    const int q  = blockIdx.x;
    const int jj = q >> 7;            // q / 128
    const int bb = q & 127;           // q % 128

    const float cx = cord[jj * BB + bb];
    const float cy = cord[JJ * BB + jj * BB + bb];
    const float w  = tw[q];

    const f32x4* p0 = (const f32x4*)(loc + (size_t)q * YX);
    const f32x4* p1 = (const f32x4*)(loc + (size_t)NTOT + (size_t)q * YX);

    f32x4 lx[UNI + 1], ly[UNI + 1];
    #pragma unroll
    for (int k = 0; k < UNI; ++k) lx[k] = p0[tid + 256 * k];
    #pragma unroll
    for (int k = 0; k < UNI; ++k) ly[k] = p1[tid + 256 * k];
    const bool has_tail = tid < TAIL;
    if (has_tail) {
        lx[UNI] = p0[UNI * 256 + tid];
        ly[UNI] = p1[UNI * 256 + tid];
    }

    float acc = 0.0f;
    #pragma unroll
    for (int k = 0; k < UNI; ++k)
        acc += tile_term(lx[k], ly[k], tid + 256 * k, cx, cy);
    if (has_tail)
        acc += tile_term(lx[UNI], ly[UNI], UNI * 256 + tid, cx, cy);

    // wave64 shuffle reduction
    #pragma unroll
    for (int off = 32; off > 0; off >>= 1)
        acc += __shfl_down(acc, off, 64);

    __shared__ float wsum[4];
    __shared__ int lastFlag;
    const int lane = tid & 63;
    const int wave = tid >> 6;
    if (lane == 0) wsum[wave] = acc;
    __syncthreads();

    if (tid == 0) {   // w is uniform per block: apply w^2 once here
        partial[q] = (w * w) * (wsum[0] + wsum[1] + wsum[2] + wsum[3]);
        __threadfence();  // release: partial visible device-wide before ticket
        const unsigned t = __hip_atomic_fetch_add(
            counter, 1u, __ATOMIC_ACQ_REL, __HIP_MEMORY_SCOPE_AGENT);
        lastFlag = (t == NQ - 1);
    }
    __syncthreads();
    if (!lastFlag) return;

    // Last block folds all NQ partials (deterministic order).
    // Agent-scope atomic loads bypass possibly-stale non-coherent caches.
    float a2 = 0.0f;
    for (int i = tid; i < NQ; i += 256)
        a2 += __hip_atomic_load(&partial[i], __ATOMIC_RELAXED,
                                __HIP_MEMORY_SCOPE_AGENT);

    #pragma unroll
    for (int off = 32; off > 0; off >>= 1)
        a2 += __shfl_down(a2, off, 64);

    __syncthreads();   // wsum reuse
    if (lane == 0) wsum[wave] = a2;
    __syncthreads();

    if (tid == 0) {
        const float s = wsum[0] + wsum[1] + wsum[2] + wsum[3];
        out[0] = s * (0.5f / (float)NTOT);   // 0.5 / (J * B * YX)
    }
}

extern "C" void kernel_launch(void* const* d_in, const int* in_sizes, int n_in,
                              void* d_out, int out_size, void* d_ws, size_t ws_size,
                              hipStream_t stream) {
    const float* loc  = (const float*)d_in[0];   // (2,128,17,96,72) fp32
    const float* cord = (const float*)d_in[1];   // (2,17,128) fp32
    const float* tw   = (const float*)d_in[2];   // (128,17,1) fp32
    float* partial = (float*)d_ws;               // NQ floats
    unsigned* counter = (unsigned*)((char*)d_ws + CTR_OFF);
    float* out = (float*)d_out;

    hipMemsetAsync(counter, 0, sizeof(unsigned), stream);  // ticket reset (ws is poisoned)
    regloss_fused_kernel<<<NQ, 256, 0, stream>>>(loc, cord, tw, partial, counter, out);
}

// Round 4
// 175.021 us; speedup vs baseline: 2.0470x; 2.0470x over previous
//
#include <hip/hip_runtime.h>

#define BB   128
#define JJ   17
#define YY   96
#define XX   72
#define YX   (YY * XX)        // 6912 floats per (b,j) per channel
#define N4   (YX / 4)         // 1728 float4s
#define NQ   (BB * JJ)        // 2176 blocks / partials
#define NTOT (NQ * YX)        // 15040512 elements per channel
#define UNI  6                // uniform float4 iters/thread (6*256 = 1536)
#define TAIL (N4 - UNI * 256) // 192 remaining float4s (threads 0..191)

typedef float f32x4 __attribute__((ext_vector_type(4)));

// Sum of squared diffs for one float4 pair at float4-index i within a q-tile.
// yy = (4i)/72 = i/18 ; xx = (i%18)*4.
// gt uses trunc-toward-zero (np int32 cast) == truncf for |z| < 2^31.
// Operand order fl((x+k) - cx) kept bit-identical to the reference.
__device__ __forceinline__ float tile_term(f32x4 lx, f32x4 ly, int i,
                                           float cx, float cy) {
    const int yy = i / 18;                // magic-mul constant divide
    const int xx = (i - yy * 18) * 4;
    const float gy = truncf((float)yy - cy);
    const float xxf = (float)xx;
    float s = 0.0f;
    #pragma unroll
    for (int k = 0; k < 4; ++k) {
        const float gx = truncf((xxf + (float)k) - cx);  // (float)(xx+k) exact
        const float dx = lx[k] - gx;
        s = fmaf(dx, dx, s);
        const float dy = ly[k] - gy;
        s = fmaf(dy, dy, s);
    }
    return s;
}

// Stage 1: one block per q = b*J + j (round-0 geometry — measured best).
// NOTE (rounds 2/3): do NOT fuse the final reduction via last-block-done.
// The per-block __threadfence + agent-scope ACQ_REL atomic emits
// buffer_wbl2/buffer_inv per block on gfx950 (non-coherent per-XCD L2s),
// stalling the TCC pipeline 2176 times -> 8x regression (231 us vs ~28 us).
// Two plain kernels with no device-scope sync are strictly faster here.
__global__ __launch_bounds__(256) void regloss_partial_kernel(
    const float* __restrict__ loc,    // (2, B, J, Y, X)
    const float* __restrict__ cord,   // (2, J, B)
    const float* __restrict__ tw,     // (B, J, 1)
    float* __restrict__ partial)      // (NQ,) in d_ws
{
    const int tid = threadIdx.x;
    const int q  = blockIdx.x;
    const int jj = q >> 7;            // q / 128
    const int bb = q & 127;           // q % 128

    const float cx = cord[jj * BB + bb];
    const float cy = cord[JJ * BB + jj * BB + bb];
    const float w  = tw[q];

    const f32x4* p0 = (const f32x4*)(loc + (size_t)q * YX);
    const f32x4* p1 = (const f32x4*)(loc + (size_t)NTOT + (size_t)q * YX);

    f32x4 lx[UNI + 1], ly[UNI + 1];
    #pragma unroll
    for (int k = 0; k < UNI; ++k) lx[k] = p0[tid + 256 * k];
    #pragma unroll
    for (int k = 0; k < UNI; ++k) ly[k] = p1[tid + 256 * k];
    const bool has_tail = tid < TAIL;
    if (has_tail) {
        lx[UNI] = p0[UNI * 256 + tid];
        ly[UNI] = p1[UNI * 256 + tid];
    }

    float acc = 0.0f;
    #pragma unroll
    for (int k = 0; k < UNI; ++k)
        acc += tile_term(lx[k], ly[k], tid + 256 * k, cx, cy);
    if (has_tail)
        acc += tile_term(lx[UNI], ly[UNI], UNI * 256 + tid, cx, cy);

    // wave64 shuffle reduction
    #pragma unroll
    for (int off = 32; off > 0; off >>= 1)
        acc += __shfl_down(acc, off, 64);

    __shared__ float wsum[4];
    const int lane = tid & 63;
    const int wave = tid >> 6;
    if (lane == 0) wsum[wave] = acc;
    __syncthreads();

    if (tid == 0)   // w is uniform per block: apply w^2 once here
        partial[q] = (w * w) * (wsum[0] + wsum[1] + wsum[2] + wsum[3]);
}

// Stage 2: single block folds the 2176 partials, scales, stores the scalar.
__global__ __launch_bounds__(256) void regloss_final_kernel(
    const float* __restrict__ partial, float* __restrict__ out)
{
    float acc = 0.0f;
    for (int i = threadIdx.x; i < NQ; i += 256)
        acc += partial[i];

    #pragma unroll
    for (int off = 32; off > 0; off >>= 1)
        acc += __shfl_down(acc, off, 64);

    __shared__ float wsum[4];
    const int lane = threadIdx.x & 63;
    const int wave = threadIdx.x >> 6;
    if (lane == 0) wsum[wave] = acc;
    __syncthreads();

    if (threadIdx.x == 0) {
        const float s = wsum[0] + wsum[1] + wsum[2] + wsum[3];
        out[0] = s * (0.5f / (float)NTOT);   // 0.5 / (J * B * YX)
    }
}

extern "C" void kernel_launch(void* const* d_in, const int* in_sizes, int n_in,
                              void* d_out, int out_size, void* d_ws, size_t ws_size,
                              hipStream_t stream) {
    const float* loc  = (const float*)d_in[0];   // (2,128,17,96,72) fp32
    const float* cord = (const float*)d_in[1];   // (2,17,128) fp32
    const float* tw   = (const float*)d_in[2];   // (128,17,1) fp32
    float* partial = (float*)d_ws;               // NQ floats, overwritten each call
    float* out = (float*)d_out;

    regloss_partial_kernel<<<NQ, 256, 0, stream>>>(loc, cord, tw, partial);
    regloss_final_kernel<<<1, 256, 0, stream>>>(partial, out);
}